// Round 1
// baseline (485.046 us; speedup 1.0000x reference)
//
#include <hip/hip_runtime.h>
#include <math.h>

// Shapes (fixed by the problem): B=32, S=512, I=64, H=512, E=8, P=96, O=64, EM=512
// D = S*I = 32768.
#define DIMK 32768

__device__ __forceinline__ void fma4(float4& a, float s, const float4 w) {
  a.x += s * w.x; a.y += s * w.y; a.z += s * w.z; a.w += s * w.w;
}

__device__ __forceinline__ float block_sum(float v, float* red, int n) {
  int t = threadIdx.x;
  red[t] = v;
  __syncthreads();
  for (int s = n >> 1; s > 0; s >>= 1) {
    if (t < s) red[t] += red[t + s];
    __syncthreads();
  }
  float r = red[0];
  __syncthreads();
  return r;
}

// ---------------------------------------------------------------------------
// Kernel 1: y1_partial = x_flat(32,32768) @ gW1(32768,512), k-split.
// grid (2 m-tiles of 256 cols, 128 k-chunks of 256), block 256.
// Thread: 16 rows x 4 cols (float4). Waves 0/1: k-parity 0, waves 2/3: parity 1.
// x staged transposed in LDS ([kk][36] float rows -> 16B aligned, broadcast reads).
__global__ __launch_bounds__(256) void gemm1_part(const float* __restrict__ x,
                                                  const float* __restrict__ gW1,
                                                  float* __restrict__ part) {
  const int mt = blockIdx.x;      // 0..1
  const int ks = blockIdx.y;      // 0..127
  const int m0 = mt * 256;
  const int t = threadIdx.x;
  const int cg = t & 63;          // 64 col-groups * 4 cols = 256 cols
  const int rh = t >> 6;          // 0..3
  const int rbase = (rh & 1) * 4; // float4-group base (rows rbase*4 .. +15)
  const int par = rh >> 1;        // k parity
  __shared__ float4 xs4[128][9];  // [kk][b/4], row stride 36 floats (16B aligned)
  __shared__ float4 red4[256];

  float4 acc[16];
#pragma unroll
  for (int r = 0; r < 16; ++r) acc[r] = make_float4(0.f, 0.f, 0.f, 0.f);

  const float* gp = gW1 + (size_t)(ks * 256) * 512 + m0 + cg * 4;

  for (int stg = 0; stg < 2; ++stg) {
    const int k0 = ks * 256 + stg * 128;
    __syncthreads();
    float* xsf = (float*)xs4;
    for (int i = t; i < 32 * 128; i += 256) {
      int b = i >> 7, kk = i & 127;
      xsf[kk * 36 + b] = x[(size_t)b * DIMK + k0 + kk];
    }
    __syncthreads();
#pragma unroll 4
    for (int kk = par; kk < 128; kk += 2) {
      float4 wv = *(const float4*)(gp + (size_t)(stg * 128 + kk) * 512);
      const float4* xr = &xs4[kk][rbase];
#pragma unroll
      for (int j = 0; j < 4; ++j) {
        float4 xv = xr[j];
        fma4(acc[j * 4 + 0], xv.x, wv);
        fma4(acc[j * 4 + 1], xv.y, wv);
        fma4(acc[j * 4 + 2], xv.z, wv);
        fma4(acc[j * 4 + 3], xv.w, wv);
      }
    }
  }

  // combine the two k-parities (waves 0/1 with 2/3), store partials
  for (int r = 0; r < 16; ++r) {
    __syncthreads();
    red4[t] = acc[r];
    __syncthreads();
    if (t < 128) {
      float4 a = red4[t], b4 = red4[t + 128];
      float4 s = make_float4(a.x + b4.x, a.y + b4.y, a.z + b4.z, a.w + b4.w);
      int row = (t >> 6) * 16 + r;
      *(float4*)(part + ((size_t)ks * 32 + row) * 512 + m0 + (t & 63) * 4) = s;
    }
  }
}

// Kernel 2: sum k-split partials + gb1 -> y1 (32x512). grid 128 (b*4 mchunks), block 128.
__global__ __launch_bounds__(128) void red_bias(const float* __restrict__ part,
                                                const float* __restrict__ gb1,
                                                float* __restrict__ y1) {
  const int b = blockIdx.x >> 2;
  const int mc = blockIdx.x & 3;
  const int m = mc * 128 + threadIdx.x;
  float s = gb1[m];
  for (int ks = 0; ks < 128; ++ks)
    s += part[((size_t)ks * 32 + b) * 512 + m];
  y1[b * 512 + m] = s;
}

// Kernel 3: LayerNorm(512) (+optional relu). grid 32, block 512.
__global__ __launch_bounds__(512) void ln512_relu(const float* __restrict__ in,
                                                  const float* __restrict__ g,
                                                  const float* __restrict__ bt,
                                                  float* __restrict__ out, int relu) {
  __shared__ float red[512];
  const int b = blockIdx.x, t = threadIdx.x;
  float a = in[b * 512 + t];
  float mean = block_sum(a, red, 512) * (1.f / 512.f);
  float d = a - mean;
  float var = block_sum(d * d, red, 512) * (1.f / 512.f);
  float v = d * rsqrtf(var + 1e-5f) * g[t] + bt[t];
  out[b * 512 + t] = relu ? fmaxf(v, 0.f) : v;
}

// Row GEMM (32 rows): out = LN(in(32x512) @ W(512x512) + bias) [*relu]. grid 32, block 512.
__global__ __launch_bounds__(512) void rowgemm512(const float* __restrict__ in,
                                                  const float* __restrict__ W,
                                                  const float* __restrict__ bias,
                                                  const float* __restrict__ g,
                                                  const float* __restrict__ bt,
                                                  float* __restrict__ out, int relu) {
  __shared__ float rs[512];
  __shared__ float red[512];
  const int b = blockIdx.x, t = threadIdx.x;
  rs[t] = in[b * 512 + t];
  __syncthreads();
  float a = bias[t];
  const float* wp = W + t;
#pragma unroll 8
  for (int k = 0; k < 512; ++k) a += rs[k] * wp[(size_t)k * 512];
  float mean = block_sum(a, red, 512) * (1.f / 512.f);
  float d = a - mean;
  float var = block_sum(d * d, red, 512) * (1.f / 512.f);
  float v = d * rsqrtf(var + 1e-5f) * g[t] + bt[t];
  out[b * 512 + t] = relu ? fmaxf(v, 0.f) : v;
}

// Kernel: emb = h2 @ gW3 + gb3; d2 to protos; softmax gate w(32x8). grid 32, block 128.
__global__ __launch_bounds__(128) void emb_gate(const float* __restrict__ h2,
                                                const float* __restrict__ gW3,
                                                const float* __restrict__ gb3,
                                                const float* __restrict__ protos,
                                                const float* __restrict__ temp,
                                                float* __restrict__ wgt) {
  __shared__ float hs[512];
  __shared__ float red[128];
  __shared__ float d2s[8];
  const int b = blockIdx.x, t = threadIdx.x;
  for (int i = t; i < 512; i += 128) hs[i] = h2[b * 512 + i];
  __syncthreads();
  float a = gb3[t];
#pragma unroll 8
  for (int k = 0; k < 512; ++k) a += hs[k] * gW3[k * 128 + t];
  for (int e = 0; e < 8; ++e) {
    float dd = a - protos[e * 128 + t];
    float s = block_sum(dd * dd, red, 128);
    if (t == 0) d2s[e] = s;
  }
  __syncthreads();
  if (t == 0) {
    float tt = fminf(fmaxf(temp[0], 0.1f), 5.0f);
    float lg[8], mx = -1e30f;
    for (int e = 0; e < 8; ++e) {
      float dist = sqrtf(fmaxf(d2s[e], 1e-12f));
      lg[e] = -dist / tt;
      mx = fmaxf(mx, lg[e]);
    }
    float se = 0.f;
    for (int e = 0; e < 8; ++e) { lg[e] = expf(lg[e] - mx); se += lg[e]; }
    for (int e = 0; e < 8; ++e) wgt[b * 8 + e] = lg[e] / se;
  }
}

// Expert path, only s = S-1 rows. grid (8 o-tiles, 8 experts, 4 h-chunks), block 256.
// Step1: he[b, h-chunk] = relu(x_last @ eW1[e] + eb1[e]) into padded LDS.
// Step2: partial eo = he @ eW2[e][h-chunk, o-tile] -> epart[hs][e][b][o].
__global__ __launch_bounds__(256) void expert5(const float* __restrict__ x,
                                               const float* __restrict__ eW1,
                                               const float* __restrict__ eb1,
                                               const float* __restrict__ eW2,
                                               float* __restrict__ epart) {
  const int ot = blockIdx.x;  // 0..7
  const int e = blockIdx.y;   // 0..7
  const int hs = blockIdx.z;  // 0..3
  const int t = threadIdx.x;
  __shared__ float xl[32 * 64];
  __shared__ float hel[32][132];  // pad 132: b-stride = 4 banks -> conflict-free
  for (int i = t; i < 2048; i += 256) {
    int b = i >> 6, ii = i & 63;
    xl[i] = x[(size_t)b * DIMK + 32704 + ii];  // x[b, S-1, ii]
  }
  __syncthreads();
  for (int idx = t; idx < 4096; idx += 256) {
    int b = idx >> 7, hh = idx & 127;
    int h = hs * 128 + hh;
    float a = eb1[e * 512 + h];
    const float* w1 = eW1 + (size_t)e * 64 * 512 + h;
    const float* xb = xl + b * 64;
#pragma unroll 8
    for (int i2 = 0; i2 < 64; ++i2) a += xb[i2] * w1[(size_t)i2 * 512];
    hel[b][hh] = fmaxf(a, 0.f);
  }
  __syncthreads();
  const int o4 = t & 15, bg = t >> 4;  // bg 0..15 -> 2 b each
  const int b0 = bg * 2;
  const int o = ot * 64 + o4 * 4;
  float4 a0 = make_float4(0.f, 0.f, 0.f, 0.f), a1 = a0;
  const float* w2 = eW2 + ((size_t)e * 512 + hs * 128) * 512 + o;
#pragma unroll 4
  for (int hh = 0; hh < 128; ++hh) {
    float4 wv = *(const float4*)(w2 + (size_t)hh * 512);
    fma4(a0, hel[b0][hh], wv);
    fma4(a1, hel[b0 + 1][hh], wv);
  }
  *(float4*)(epart + (((size_t)hs * 8 + e) * 32 + b0) * 512 + o) = a0;
  *(float4*)(epart + (((size_t)hs * 8 + e) * 32 + b0 + 1) * 512 + o) = a1;
}

// fused_last[b][o] = sum_e w[b,e] * (sum_hs epart + eb2[e,o]). grid 32, block 512.
__global__ __launch_bounds__(512) void fuse6a(const float* __restrict__ epart,
                                              const float* __restrict__ eb2,
                                              const float* __restrict__ wgt,
                                              float* __restrict__ fusedv) {
  const int b = blockIdx.x, o = threadIdx.x;
  float s = 0.f;
  for (int e = 0; e < 8; ++e) {
    float acc = eb2[e * 512 + o];
    for (int hsv = 0; hsv < 4; ++hsv)
      acc += epart[(((size_t)hsv * 8 + e) * 32 + b) * 512 + o];
    s += wgt[b * 8 + e] * acc;
  }
  fusedv[b * 512 + o] = s;
}

// pp = relu(LN(last @ pW1(512x256) + pb1)). grid 32, block 256.
__global__ __launch_bounds__(256) void rowgemm_p1(const float* __restrict__ in,
                                                  const float* __restrict__ pW1,
                                                  const float* __restrict__ pb1,
                                                  const float* __restrict__ g,
                                                  const float* __restrict__ bt,
                                                  float* __restrict__ pp) {
  __shared__ float rs[512];
  __shared__ float red[256];
  const int b = blockIdx.x, t = threadIdx.x;
  rs[t] = in[b * 512 + t];
  rs[t + 256] = in[b * 512 + t + 256];
  __syncthreads();
  float a = pb1[t];
#pragma unroll 8
  for (int k = 0; k < 512; ++k) a += rs[k] * pW1[(size_t)k * 256 + t];
  float mean = block_sum(a, red, 256) * (1.f / 256.f);
  float d = a - mean;
  float var = block_sum(d * d, red, 256) * (1.f / 256.f);
  float v = d * rsqrtf(var + 1e-5f) * g[t] + bt[t];
  pp[b * 256 + t] = fmaxf(v, 0.f);
}

// p = pp(32x256) @ pW2(256x6144) + pb2, reshape (32,96,64), LN over O=64 -> out.
// grid (96 p-tiles, 4 b-quads), block 64. Thread: 4 o (float4) x 2 b.
__global__ __launch_bounds__(64) void final9(const float* __restrict__ pp,
                                             const float* __restrict__ pW2,
                                             const float* __restrict__ pb2,
                                             const float* __restrict__ ong,
                                             const float* __restrict__ onb,
                                             float* __restrict__ out) {
  const int pi = blockIdx.x;  // 0..95
  const int bq = blockIdx.y;  // 0..3
  const int t = threadIdx.x;  // 64
  const int o4 = t & 15, bsub = t >> 4;  // bsub 0..3
  __shared__ float pplT[256][9];  // [k][b within quad], pad 9 -> conflict-free
  for (int i = t; i < 8 * 256; i += 64) {
    int bb = i >> 8, k = i & 255;
    pplT[k][bb] = pp[(bq * 8 + bb) * 256 + k];
  }
  __syncthreads();
  const int b0 = bsub * 2;
  const int o = pi * 64 + o4 * 4;
  float4 a0 = make_float4(0.f, 0.f, 0.f, 0.f), a1 = a0;
  const float* wp = pW2 + o;
#pragma unroll 4
  for (int k = 0; k < 256; ++k) {
    float4 wv = *(const float4*)(wp + (size_t)k * 6144);
    fma4(a0, pplT[k][b0], wv);
    fma4(a1, pplT[k][b0 + 1], wv);
  }
  float4 bias = *(const float4*)(pb2 + o);
  a0.x += bias.x; a0.y += bias.y; a0.z += bias.z; a0.w += bias.w;
  a1.x += bias.x; a1.y += bias.y; a1.z += bias.z; a1.w += bias.w;

  float4 gv = *(const float4*)(ong + o4 * 4);
  float4 bv = *(const float4*)(onb + o4 * 4);
  float4 accs[2] = {a0, a1};
#pragma unroll
  for (int rr = 0; rr < 2; ++rr) {
    float4 a = accs[rr];
    float s = a.x + a.y + a.z + a.w;
    s += __shfl_xor(s, 1); s += __shfl_xor(s, 2);
    s += __shfl_xor(s, 4); s += __shfl_xor(s, 8);
    float mean = s * (1.f / 64.f);
    float d0 = a.x - mean, d1 = a.y - mean, d2 = a.z - mean, d3 = a.w - mean;
    float q = d0 * d0 + d1 * d1 + d2 * d2 + d3 * d3;
    q += __shfl_xor(q, 1); q += __shfl_xor(q, 2);
    q += __shfl_xor(q, 4); q += __shfl_xor(q, 8);
    float r = rsqrtf(q * (1.f / 64.f) + 1e-5f);
    float4 res;
    res.x = d0 * r * gv.x + bv.x;
    res.y = d1 * r * gv.y + bv.y;
    res.z = d2 * r * gv.z + bv.z;
    res.w = d3 * r * gv.w + bv.w;
    int b = bq * 8 + b0 + rr;
    *(float4*)(out + ((size_t)b * 96 + pi) * 64 + o4 * 4) = res;
  }
}

extern "C" void kernel_launch(void* const* d_in, const int* in_sizes, int n_in,
                              void* d_out, int out_size, void* d_ws, size_t ws_size,
                              hipStream_t stream) {
  (void)in_sizes; (void)n_in; (void)out_size; (void)ws_size;
  const float* x      = (const float*)d_in[0];
  const float* gW1    = (const float*)d_in[1];
  const float* gb1    = (const float*)d_in[2];
  const float* gln1_g = (const float*)d_in[3];
  const float* gln1_b = (const float*)d_in[4];
  const float* gW2    = (const float*)d_in[5];
  const float* gb2    = (const float*)d_in[6];
  const float* gln2_g = (const float*)d_in[7];
  const float* gln2_b = (const float*)d_in[8];
  const float* gW3    = (const float*)d_in[9];
  const float* gb3    = (const float*)d_in[10];
  const float* protos = (const float*)d_in[11];
  const float* temp   = (const float*)d_in[12];
  const float* eW1    = (const float*)d_in[13];
  const float* eb1    = (const float*)d_in[14];
  const float* eW2    = (const float*)d_in[15];
  const float* eb2    = (const float*)d_in[16];
  const float* fW1    = (const float*)d_in[17];
  const float* fb1    = (const float*)d_in[18];
  const float* fln_g  = (const float*)d_in[19];
  const float* fln_b  = (const float*)d_in[20];
  const float* fW2    = (const float*)d_in[21];
  const float* fb2    = (const float*)d_in[22];
  const float* ln_g   = (const float*)d_in[23];
  const float* ln_b   = (const float*)d_in[24];
  const float* pW1    = (const float*)d_in[25];
  const float* pb1    = (const float*)d_in[26];
  const float* pln_g  = (const float*)d_in[27];
  const float* pln_b  = (const float*)d_in[28];
  const float* pW2    = (const float*)d_in[29];
  const float* pb2    = (const float*)d_in[30];
  const float* on_g   = (const float*)d_in[31];
  const float* on_b   = (const float*)d_in[32];
  float* out = (float*)d_out;

  float* ws     = (float*)d_ws;
  float* part   = ws;               // 128*32*512 = 2,097,152 floats
  float* y1     = part + 2097152;   // 16384
  float* h1     = y1 + 16384;       // 16384
  float* h2     = h1 + 16384;       // 16384
  float* wgt    = h2 + 16384;       // 256
  float* epart  = wgt + 256;        // 4*8*32*512 = 524288
  float* fusedv = epart + 524288;   // 16384
  float* ff1    = fusedv + 16384;   // 16384
  float* lastv  = ff1 + 16384;      // 16384
  float* pp     = lastv + 16384;    // 8192

  gemm1_part<<<dim3(2, 128), 256, 0, stream>>>(x, gW1, part);
  red_bias<<<128, 128, 0, stream>>>(part, gb1, y1);
  ln512_relu<<<32, 512, 0, stream>>>(y1, gln1_g, gln1_b, h1, 1);
  rowgemm512<<<32, 512, 0, stream>>>(h1, gW2, gb2, gln2_g, gln2_b, h2, 1);
  emb_gate<<<32, 128, 0, stream>>>(h2, gW3, gb3, protos, temp, wgt);
  expert5<<<dim3(8, 8, 4), 256, 0, stream>>>(x, eW1, eb1, eW2, epart);
  fuse6a<<<32, 512, 0, stream>>>(epart, eb2, wgt, fusedv);
  rowgemm512<<<32, 512, 0, stream>>>(fusedv, fW1, fb1, fln_g, fln_b, ff1, 1);
  rowgemm512<<<32, 512, 0, stream>>>(ff1, fW2, fb2, ln_g, ln_b, lastv, 0);
  rowgemm_p1<<<32, 256, 0, stream>>>(lastv, pW1, pb1, pln_g, pln_b, pp);
  final9<<<dim3(96, 4), 64, 0, stream>>>(pp, pW2, pb2, on_g, on_b, out);
}

// Round 2
// 449.891 us; speedup vs baseline: 1.0781x; 1.0781x over previous
//
#include <hip/hip_runtime.h>
#include <math.h>

// Shapes: B=32, S=512, I=64, H=512, E=8, P=96, O=64, EM=512; D = S*I = 32768.
#define DIMK 32768

__device__ __forceinline__ void fma4(float4& a, float s, const float4 w) {
  a.x += s * w.x; a.y += s * w.y; a.z += s * w.z; a.w += s * w.w;
}

__device__ __forceinline__ float block_sum(float v, float* red, int n) {
  int t = threadIdx.x;
  red[t] = v;
  __syncthreads();
  for (int s = n >> 1; s > 0; s >>= 1) {
    if (t < s) red[t] += red[t + s];
    __syncthreads();
  }
  float r = red[0];
  __syncthreads();
  return r;
}

// ---------------------------------------------------------------------------
// Kernel 1: y1_partial = x_flat(32,32768) @ gW1(32768,512), k-split.
// grid (4 m-tiles of 128 cols, 128 k-chunks of 256), block 512 (8 waves).
// Thread: 16 rows x 4 cols (float4), 8-way k-parity across thread-halves.
// 512 blocks -> 2 blocks/CU, 16 waves/CU (vs 4 last round).
__global__ __launch_bounds__(512, 4) void gemm1_part(const float* __restrict__ x,
                                                     const float* __restrict__ gW1,
                                                     float* __restrict__ part) {
  const int mt = blockIdx.x;      // 0..3
  const int ks = blockIdx.y;      // 0..127
  const int m0 = mt * 128;
  const int k0 = ks * 256;
  const int t = threadIdx.x;
  const int cg = t & 31;          // 32 col-groups * 4 cols = 128 cols
  const int rh = t >> 5;          // 0..15
  const int rbase = (rh & 1) * 4; // float4-group base: rows 0-15 or 16-31
  const int par = rh >> 1;        // k parity 0..7
  __shared__ float4 xs4[256][9];  // [kk][b/4], row stride 36 floats
  __shared__ float4 red4[512];

  float4 acc[16];
#pragma unroll
  for (int r = 0; r < 16; ++r) acc[r] = make_float4(0.f, 0.f, 0.f, 0.f);

  // stage x[all 32 b][k0..k0+256) transposed into LDS
  float* xsf = (float*)xs4;
  for (int i = t; i < 32 * 256; i += 512) {
    int bb = i >> 8, kk = i & 255;
    xsf[kk * 36 + bb] = x[(size_t)bb * DIMK + k0 + kk];
  }
  __syncthreads();

  const float* gp = gW1 + (size_t)k0 * 512 + m0 + cg * 4;
#pragma unroll 2
  for (int kk = par; kk < 256; kk += 8) {
    float4 wv = *(const float4*)(gp + (size_t)kk * 512);
    const float4* xr = &xs4[kk][rbase];
#pragma unroll
    for (int j = 0; j < 4; ++j) {
      float4 xv = xr[j];
      fma4(acc[j * 4 + 0], xv.x, wv);
      fma4(acc[j * 4 + 1], xv.y, wv);
      fma4(acc[j * 4 + 2], xv.z, wv);
      fma4(acc[j * 4 + 3], xv.w, wv);
    }
  }

  // combine the 8 k-parities, store partials
  for (int r = 0; r < 16; ++r) {
    __syncthreads();
    red4[t] = acc[r];
    __syncthreads();
    if (t < 64) {
      float4 s = red4[t];
#pragma unroll
      for (int p = 1; p < 8; ++p) {
        float4 q = red4[t + 64 * p];
        s.x += q.x; s.y += q.y; s.z += q.z; s.w += q.w;
      }
      int row = (t >> 5) * 16 + r;
      *(float4*)(part + ((size_t)ks * 32 + row) * 512 + m0 + (t & 31) * 4) = s;
    }
  }
}

// ---------------------------------------------------------------------------
// gtail: per b (grid 32, block 512):
//   A: y1 = sum_ks part + gb1; h1 = relu(LN(y1))
//   B: h2 = relu(LN(h1@gW2+gb2))
//   C: emb = h2@gW3+gb3  (4-way k-split over threads)
//   D: d2[e] via one wave per expert; E: softmax gate -> wgt
__global__ __launch_bounds__(512) void gtail(const float* __restrict__ part,
                                             const float* __restrict__ gb1,
                                             const float* __restrict__ g1g, const float* __restrict__ g1b,
                                             const float* __restrict__ gW2, const float* __restrict__ gb2,
                                             const float* __restrict__ g2g, const float* __restrict__ g2b,
                                             const float* __restrict__ gW3, const float* __restrict__ gb3,
                                             const float* __restrict__ protos, const float* __restrict__ temp,
                                             float* __restrict__ wgt) {
  const int b = blockIdx.x, t = threadIdx.x;
  __shared__ float h1s[512], h2s[512], red[512];
  __shared__ float cpart[4][128];
  __shared__ float embs[128];
  __shared__ float d2s[8];

  // A: reduce 128 k-split partials
  float a = gb1[t];
  const float* pp0 = part + (size_t)b * 512 + t;
#pragma unroll 16
  for (int ks = 0; ks < 128; ++ks) a += pp0[(size_t)ks * 16384];
  float mean = block_sum(a, red, 512) * (1.f / 512.f);
  float d = a - mean;
  float var = block_sum(d * d, red, 512) * (1.f / 512.f);
  h1s[t] = fmaxf(d * rsqrtf(var + 1e-5f) * g1g[t] + g1b[t], 0.f);
  __syncthreads();

  // B: h2 = relu(LN(h1@gW2+gb2))
  float a2 = gb2[t];
  const float* wp = gW2 + t;
#pragma unroll 8
  for (int k = 0; k < 512; ++k) a2 += h1s[k] * wp[(size_t)k * 512];
  mean = block_sum(a2, red, 512) * (1.f / 512.f);
  d = a2 - mean;
  var = block_sum(d * d, red, 512) * (1.f / 512.f);
  h2s[t] = fmaxf(d * rsqrtf(var + 1e-5f) * g2g[t] + g2b[t], 0.f);
  __syncthreads();

  // C: emb (128) with 4-way k split
  {
    const int m = t & 127, kq = t >> 7;
    float c = 0.f;
    const float* w3 = gW3 + m;
#pragma unroll 8
    for (int k = kq * 128; k < kq * 128 + 128; ++k) c += h2s[k] * w3[(size_t)k * 128];
    cpart[kq][m] = c;
  }
  __syncthreads();
  if (t < 128) embs[t] = gb3[t] + cpart[0][t] + cpart[1][t] + cpart[2][t] + cpart[3][t];
  __syncthreads();

  // D: one wave per expert
  {
    const int w = t >> 6, l = t & 63;
    float d0 = embs[l] - protos[w * 128 + l];
    float d1 = embs[l + 64] - protos[w * 128 + l + 64];
    float q = d0 * d0 + d1 * d1;
    q += __shfl_xor(q, 1);  q += __shfl_xor(q, 2);  q += __shfl_xor(q, 4);
    q += __shfl_xor(q, 8);  q += __shfl_xor(q, 16); q += __shfl_xor(q, 32);
    if (l == 0) d2s[w] = q;
  }
  __syncthreads();

  // E: softmax gate
  if (t == 0) {
    float tt = fminf(fmaxf(temp[0], 0.1f), 5.0f);
    float lg[8], mx = -1e30f;
#pragma unroll
    for (int e = 0; e < 8; ++e) {
      float dist = sqrtf(fmaxf(d2s[e], 1e-12f));
      lg[e] = -dist / tt;
      mx = fmaxf(mx, lg[e]);
    }
    float se = 0.f;
#pragma unroll
    for (int e = 0; e < 8; ++e) { lg[e] = expf(lg[e] - mx); se += lg[e]; }
#pragma unroll
    for (int e = 0; e < 8; ++e) wgt[b * 8 + e] = lg[e] / se;
  }
}

// ---------------------------------------------------------------------------
// Expert path, only s = S-1. grid (8 o-tiles, 8 experts, 2 b-halves), block 256.
// Step1: he = relu(x_last @ eW1[e] + eb1[e]) for 16 b, all 512 h -> LDS.
// Step2: eo = he @ eW2[e][:, o-tile] -> epart[e][b][o]  (full K, no hs split).
__global__ __launch_bounds__(256) void expert5(const float* __restrict__ x,
                                               const float* __restrict__ eW1,
                                               const float* __restrict__ eb1,
                                               const float* __restrict__ eW2,
                                               float* __restrict__ epart) {
  const int ot = blockIdx.x;  // 0..7
  const int e = blockIdx.y;   // 0..7
  const int bh = blockIdx.z;  // 0..1
  const int t = threadIdx.x;
  __shared__ float xl[16 * 64];
  __shared__ float hel[16][516];  // stride 516: banks 4*b+h -> conflict-free reads
  for (int i = t; i < 1024; i += 256) {
    int bb = i >> 6, ii = i & 63;
    xl[i] = x[(size_t)(bh * 16 + bb) * DIMK + 32704 + ii];  // x[b, S-1, ii]
  }
  __syncthreads();
  for (int idx = t; idx < 16 * 512; idx += 256) {
    int bb = idx >> 9, h = idx & 511;
    float a = eb1[e * 512 + h];
    const float* w1 = eW1 + (size_t)e * 64 * 512 + h;
    const float* xb = xl + bb * 64;
#pragma unroll 8
    for (int i2 = 0; i2 < 64; ++i2) a += xb[i2] * w1[(size_t)i2 * 512];
    hel[bb][h] = fmaxf(a, 0.f);
  }
  __syncthreads();
  const int o4 = t & 15, bl = t >> 4;  // 16 b x 16 o-groups
  const int o = ot * 64 + o4 * 4;
  float4 acc = make_float4(0.f, 0.f, 0.f, 0.f);
  const float* w2 = eW2 + (size_t)e * 512 * 512 + o;
#pragma unroll 4
  for (int hh = 0; hh < 512; ++hh) {
    float4 wv = *(const float4*)(w2 + (size_t)hh * 512);
    fma4(acc, hel[bl][hh], wv);
  }
  *(float4*)(epart + ((size_t)e * 32 + bh * 16 + bl) * 512 + o) = acc;
}

// ---------------------------------------------------------------------------
// ftail: per b (grid 32, block 512):
//   0: fused = sum_e w[b,e]*(eo[e,b,:]+eb2[e])
//   1: f1 = relu(LN(fused@fW1+fb1))
//   2: last = LN(f1@fW2+fb2)
//   3: pp = relu(LN(last@pW1+pb1))  (2-way k-split, LN over 256)
__global__ __launch_bounds__(512) void ftail(const float* __restrict__ epart,
                                             const float* __restrict__ eb2,
                                             const float* __restrict__ wgt,
                                             const float* __restrict__ fW1, const float* __restrict__ fb1,
                                             const float* __restrict__ flg, const float* __restrict__ flb,
                                             const float* __restrict__ fW2, const float* __restrict__ fb2,
                                             const float* __restrict__ lng, const float* __restrict__ lnb,
                                             const float* __restrict__ pW1, const float* __restrict__ pb1,
                                             const float* __restrict__ plg, const float* __restrict__ plb,
                                             float* __restrict__ pp) {
  const int b = blockIdx.x, t = threadIdx.x;
  __shared__ float ffs[512], f1s[512], lastr[512], red[512];
  __shared__ float pl[2][256];
  __shared__ float wl[8];
  if (t < 8) wl[t] = wgt[b * 8 + t];
  __syncthreads();

  // 0: weighted expert fuse
  float a = 0.f;
#pragma unroll
  for (int e = 0; e < 8; ++e)
    a += wl[e] * (epart[((size_t)e * 32 + b) * 512 + t] + eb2[e * 512 + t]);
  ffs[t] = a;
  __syncthreads();

  // 1: f1 = relu(LN(ffs@fW1+fb1))
  float a1 = fb1[t];
  {
    const float* wp = fW1 + t;
#pragma unroll 8
    for (int k = 0; k < 512; ++k) a1 += ffs[k] * wp[(size_t)k * 512];
  }
  float mean = block_sum(a1, red, 512) * (1.f / 512.f);
  float d = a1 - mean;
  float var = block_sum(d * d, red, 512) * (1.f / 512.f);
  f1s[t] = fmaxf(d * rsqrtf(var + 1e-5f) * flg[t] + flb[t], 0.f);
  __syncthreads();

  // 2: last = LN(f1@fW2+fb2)
  float a2 = fb2[t];
  {
    const float* wp = fW2 + t;
#pragma unroll 8
    for (int k = 0; k < 512; ++k) a2 += f1s[k] * wp[(size_t)k * 512];
  }
  mean = block_sum(a2, red, 512) * (1.f / 512.f);
  d = a2 - mean;
  var = block_sum(d * d, red, 512) * (1.f / 512.f);
  lastr[t] = d * rsqrtf(var + 1e-5f) * lng[t] + lnb[t];
  __syncthreads();

  // 3: pp = relu(LN(last@pW1+pb1)), 2-way k-split
  {
    const int j = t & 255, half = t >> 8;
    float c = 0.f;
    const float* wp = pW1 + j;
#pragma unroll 8
    for (int k = half * 256; k < half * 256 + 256; ++k) c += lastr[k] * wp[(size_t)k * 256];
    pl[half][j] = c;
  }
  __syncthreads();
  float val = 0.f;
  if (t < 256) val = pl[0][t] + pl[1][t] + pb1[t];
  mean = block_sum(t < 256 ? val : 0.f, red, 512) * (1.f / 256.f);
  d = val - mean;
  var = block_sum(t < 256 ? d * d : 0.f, red, 512) * (1.f / 256.f);
  if (t < 256) pp[b * 256 + t] = fmaxf(d * rsqrtf(var + 1e-5f) * plg[t] + plb[t], 0.f);
}

// ---------------------------------------------------------------------------
// final: p = pp(32x256)@pW2(256x6144)+pb2, reshape (32,96,64), LN over O=64.
// grid (96 p-tiles, 4 b-quads), block 64.
__global__ __launch_bounds__(64) void final9(const float* __restrict__ pp,
                                             const float* __restrict__ pW2,
                                             const float* __restrict__ pb2,
                                             const float* __restrict__ ong,
                                             const float* __restrict__ onb,
                                             float* __restrict__ out) {
  const int pi = blockIdx.x;  // 0..95
  const int bq = blockIdx.y;  // 0..3
  const int t = threadIdx.x;  // 64
  const int o4 = t & 15, bsub = t >> 4;  // bsub 0..3
  __shared__ float pplT[256][9];  // [k][b within quad], pad 9 -> conflict-free
  for (int i = t; i < 8 * 256; i += 64) {
    int bb = i >> 8, k = i & 255;
    pplT[k][bb] = pp[(bq * 8 + bb) * 256 + k];
  }
  __syncthreads();
  const int b0 = bsub * 2;
  const int o = pi * 64 + o4 * 4;
  float4 a0 = make_float4(0.f, 0.f, 0.f, 0.f), a1 = a0;
  const float* wp = pW2 + o;
#pragma unroll 4
  for (int k = 0; k < 256; ++k) {
    float4 wv = *(const float4*)(wp + (size_t)k * 6144);
    fma4(a0, pplT[k][b0], wv);
    fma4(a1, pplT[k][b0 + 1], wv);
  }
  float4 bias = *(const float4*)(pb2 + o);
  a0.x += bias.x; a0.y += bias.y; a0.z += bias.z; a0.w += bias.w;
  a1.x += bias.x; a1.y += bias.y; a1.z += bias.z; a1.w += bias.w;

  float4 gv = *(const float4*)(ong + o4 * 4);
  float4 bv = *(const float4*)(onb + o4 * 4);
  float4 accs[2] = {a0, a1};
#pragma unroll
  for (int rr = 0; rr < 2; ++rr) {
    float4 a = accs[rr];
    float s = a.x + a.y + a.z + a.w;
    s += __shfl_xor(s, 1); s += __shfl_xor(s, 2);
    s += __shfl_xor(s, 4); s += __shfl_xor(s, 8);
    float mean = s * (1.f / 64.f);
    float d0 = a.x - mean, d1 = a.y - mean, d2 = a.z - mean, d3 = a.w - mean;
    float q = d0 * d0 + d1 * d1 + d2 * d2 + d3 * d3;
    q += __shfl_xor(q, 1); q += __shfl_xor(q, 2);
    q += __shfl_xor(q, 4); q += __shfl_xor(q, 8);
    float r = rsqrtf(q * (1.f / 64.f) + 1e-5f);
    float4 res;
    res.x = d0 * r * gv.x + bv.x;
    res.y = d1 * r * gv.y + bv.y;
    res.z = d2 * r * gv.z + bv.z;
    res.w = d3 * r * gv.w + bv.w;
    int b = bq * 8 + b0 + rr;
    *(float4*)(out + ((size_t)b * 96 + pi) * 64 + o4 * 4) = res;
  }
}

extern "C" void kernel_launch(void* const* d_in, const int* in_sizes, int n_in,
                              void* d_out, int out_size, void* d_ws, size_t ws_size,
                              hipStream_t stream) {
  (void)in_sizes; (void)n_in; (void)out_size; (void)ws_size;
  const float* x      = (const float*)d_in[0];
  const float* gW1    = (const float*)d_in[1];
  const float* gb1    = (const float*)d_in[2];
  const float* gln1_g = (const float*)d_in[3];
  const float* gln1_b = (const float*)d_in[4];
  const float* gW2    = (const float*)d_in[5];
  const float* gb2    = (const float*)d_in[6];
  const float* gln2_g = (const float*)d_in[7];
  const float* gln2_b = (const float*)d_in[8];
  const float* gW3    = (const float*)d_in[9];
  const float* gb3    = (const float*)d_in[10];
  const float* protos = (const float*)d_in[11];
  const float* temp   = (const float*)d_in[12];
  const float* eW1    = (const float*)d_in[13];
  const float* eb1    = (const float*)d_in[14];
  const float* eW2    = (const float*)d_in[15];
  const float* eb2    = (const float*)d_in[16];
  const float* fW1    = (const float*)d_in[17];
  const float* fb1    = (const float*)d_in[18];
  const float* fln_g  = (const float*)d_in[19];
  const float* fln_b  = (const float*)d_in[20];
  const float* fW2    = (const float*)d_in[21];
  const float* fb2    = (const float*)d_in[22];
  const float* ln_g   = (const float*)d_in[23];
  const float* ln_b   = (const float*)d_in[24];
  const float* pW1    = (const float*)d_in[25];
  const float* pb1    = (const float*)d_in[26];
  const float* pln_g  = (const float*)d_in[27];
  const float* pln_b  = (const float*)d_in[28];
  const float* pW2    = (const float*)d_in[29];
  const float* pb2    = (const float*)d_in[30];
  const float* on_g   = (const float*)d_in[31];
  const float* on_b   = (const float*)d_in[32];
  float* out = (float*)d_out;

  float* ws    = (float*)d_ws;
  float* part  = ws;               // 128*32*512 = 2,097,152 floats (8 MB)
  float* epart = part + 2097152;   // 8*32*512 = 131,072
  float* wgt   = epart + 131072;   // 256
  float* pp    = wgt + 256;        // 8192

  gemm1_part<<<dim3(4, 128), 512, 0, stream>>>(x, gW1, part);
  expert5<<<dim3(8, 8, 2), 256, 0, stream>>>(x, eW1, eb1, eW2, epart);
  gtail<<<32, 512, 0, stream>>>(part, gb1, gln1_g, gln1_b, gW2, gb2, gln2_g, gln2_b,
                                gW3, gb3, protos, temp, wgt);
  ftail<<<32, 512, 0, stream>>>(epart, eb2, wgt, fW1, fb1, fln_g, fln_b,
                                fW2, fb2, ln_g, ln_b, pW1, pb1, pln_g, pln_b, pp);
  final9<<<dim3(96, 4), 64, 0, stream>>>(pp, pW2, pb2, on_g, on_b, out);
}